// Round 2
// baseline (1205.789 us; speedup 1.0000x reference)
//
#include <hip/hip_runtime.h>
#include <math.h>

#define BB 8
#define NN 1024
#define HH 32
#define CC 64
#define II 192   // K * C = 3*64
#define DD 16
#define BN (BB*NN)

// ---------------------------------------------------------------------------
// build x_g columns [0:64): x_g[:,0:32)=cur, x_g[:,32:64)= state (or z*state)
// ---------------------------------------------------------------------------
__global__ __launch_bounds__(256) void build_xg(
    const float* __restrict__ cur,    // [BN,32]
    const float* __restrict__ state,  // [BN,32]
    const float* __restrict__ zr,     // [BN,64] or nullptr; uses z = zr[:, :32]
    float* __restrict__ xg)           // [BN,192]
{
  int idx = blockIdx.x * 256 + threadIdx.x;   // over BN*32
  int bn = idx >> 5, c = idx & 31;
  float av = cur[idx];
  float sv = state[idx];
  if (zr) sv *= zr[(size_t)bn * 64 + c];
  xg[(size_t)bn * II + c] = av;
  xg[(size_t)bn * II + 32 + c] = sv;
}

// ---------------------------------------------------------------------------
// propagation GEMM: per batch b, rows m0..m0+63:
//   acc[m, c] = sum_k S[m,k] * xg[b,k, co_in + c]   (c in 0..63)
// mode 0: xg[b,m,co_out+c] = acc
// mode 1: xg[b,m,co_out+c] = 2*acc - xg[b,m,c]   (Chebyshev T2)
// ---------------------------------------------------------------------------
__global__ __launch_bounds__(256) void prop_gemm(
    const float* __restrict__ S,
    float* __restrict__ xg,
    int co_in, int co_out, int mode)
{
  __shared__ float sS[64][33];   // [row][k], padded
  __shared__ float sX[32][64];   // [k][col]
  const int b = blockIdx.y;
  const int m0 = blockIdx.x * 64;
  float* xgb = xg + (size_t)b * NN * II;
  const int tid = threadIdx.x;
  const int tx = tid & 15, ty = tid >> 4;
  float acc[4][4] = {};

  for (int k0 = 0; k0 < NN; k0 += 32) {
#pragma unroll
    for (int q = 0; q < 2; ++q) {          // 512 float4 = 2048 floats of S tile
      int f = tid + q * 256;
      int r = f >> 3;
      int k4 = (f & 7) << 2;
      float4 v = *(const float4*)(S + (size_t)(m0 + r) * NN + k0 + k4);
      sS[r][k4 + 0] = v.x; sS[r][k4 + 1] = v.y;
      sS[r][k4 + 2] = v.z; sS[r][k4 + 3] = v.w;
    }
#pragma unroll
    for (int q = 0; q < 2; ++q) {          // X tile 32x64
      int f = tid + q * 256;
      int k = f >> 4;
      int c4 = (f & 15) << 2;
      *(float4*)&sX[k][c4] =
          *(const float4*)(xgb + (size_t)(k0 + k) * II + co_in + c4);
    }
    __syncthreads();
#pragma unroll
    for (int kk = 0; kk < 32; ++kk) {
      float a0 = sS[ty * 4 + 0][kk];
      float a1 = sS[ty * 4 + 1][kk];
      float a2 = sS[ty * 4 + 2][kk];
      float a3 = sS[ty * 4 + 3][kk];
      float4 b4 = *(const float4*)&sX[kk][tx * 4];
      acc[0][0] += a0 * b4.x; acc[0][1] += a0 * b4.y; acc[0][2] += a0 * b4.z; acc[0][3] += a0 * b4.w;
      acc[1][0] += a1 * b4.x; acc[1][1] += a1 * b4.y; acc[1][2] += a1 * b4.z; acc[1][3] += a1 * b4.w;
      acc[2][0] += a2 * b4.x; acc[2][1] += a2 * b4.y; acc[2][2] += a2 * b4.z; acc[2][3] += a2 * b4.w;
      acc[3][0] += a3 * b4.x; acc[3][1] += a3 * b4.y; acc[3][2] += a3 * b4.z; acc[3][3] += a3 * b4.w;
    }
    __syncthreads();
  }

#pragma unroll
  for (int j = 0; j < 4; ++j) {
    int row = m0 + ty * 4 + j;
    float* dst = xgb + (size_t)row * II + co_out + tx * 4;
    if (mode == 0) {
      dst[0] = acc[j][0]; dst[1] = acc[j][1]; dst[2] = acc[j][2]; dst[3] = acc[j][3];
    } else {
      const float* x0 = xgb + (size_t)row * II + tx * 4;
      dst[0] = 2.f * acc[j][0] - x0[0];
      dst[1] = 2.f * acc[j][1] - x0[1];
      dst[2] = 2.f * acc[j][2] - x0[2];
      dst[3] = 2.f * acc[j][3] - x0[3];
    }
  }
}

// ---------------------------------------------------------------------------
// meta contraction: out[bn,o] = act( sum_{d,i} emb[bn,d]*xg[bn,i]*W[d,i,o]
//                                    + sum_d emb[bn,d]*bias[d,o] )
// MODE 0 (gate, O=64): out0 = sigmoid(...)  -> z_r
// MODE 1 (upd,  O=32): hc = tanh(...); r = zr[:,32+o];
//                      res = r*state + (1-r)*hc -> out0 (and out1 if set)
// ---------------------------------------------------------------------------
template <int O, int MODE>
__global__ __launch_bounds__(256) void contract_kern(
    const float* __restrict__ xg,     // [BN,192]
    const float* __restrict__ emb,    // [BN,16]
    const float* __restrict__ W,      // [16,192,O]
    const float* __restrict__ bias,   // [16,O]
    const float* __restrict__ zr_in,  // [BN,64]  (MODE 1)
    const float* __restrict__ state,  // [BN,32]  (MODE 1)
    float* __restrict__ out0,
    float* __restrict__ out1)
{
  constexpr int TXN  = O / 4;        // threads along O
  constexpr int ROWT = 256 / TXN;    // threads along M
  constexpr int MT   = ROWT * 4;     // node tile
  __shared__ float A_lds[MT][97];
  __shared__ float B_lds[96][O];
  __shared__ float emb_lds[MT][17];

  const int bn0 = blockIdx.x * MT;
  const int tid = threadIdx.x;
  const int tx = tid % TXN, ty = tid / TXN;

  for (int f = tid; f < MT * 4; f += 256) {   // emb tile (MT x 16)
    int m = f >> 2, d4 = (f & 3) << 2;
    float4 v = *(const float4*)(emb + (size_t)(bn0 + m) * DD + d4);
    emb_lds[m][d4 + 0] = v.x; emb_lds[m][d4 + 1] = v.y;
    emb_lds[m][d4 + 2] = v.z; emb_lds[m][d4 + 3] = v.w;
  }
  __syncthreads();

  float acc[4][4] = {};
  for (int c = 0; c < 32; ++c) {       // 32 chunks of K'=96 (half of one d)
    int d = c >> 1;
    int i0 = (c & 1) * 96;
    for (int f = tid; f < MT * 24; f += 256) {   // A tile: emb*xg on the fly
      int m = f / 24;
      int t4 = (f % 24) << 2;
      float4 v = *(const float4*)(xg + (size_t)(bn0 + m) * II + i0 + t4);
      float e = emb_lds[m][d];
      A_lds[m][t4 + 0] = e * v.x; A_lds[m][t4 + 1] = e * v.y;
      A_lds[m][t4 + 2] = e * v.z; A_lds[m][t4 + 3] = e * v.w;
    }
    for (int f = tid; f < 24 * O; f += 256) {    // B tile: W[d, i0..i0+95, :]
      int t = f / TXN;
      int o4 = (f % TXN) << 2;
      *(float4*)&B_lds[t][o4] =
          *(const float4*)(W + ((size_t)d * II + i0 + t) * O + o4);
    }
    __syncthreads();
#pragma unroll 8
    for (int kk = 0; kk < 96; ++kk) {
      float a0 = A_lds[ty * 4 + 0][kk];
      float a1 = A_lds[ty * 4 + 1][kk];
      float a2 = A_lds[ty * 4 + 2][kk];
      float a3 = A_lds[ty * 4 + 3][kk];
      float4 b4 = *(const float4*)&B_lds[kk][tx * 4];
      acc[0][0] += a0 * b4.x; acc[0][1] += a0 * b4.y; acc[0][2] += a0 * b4.z; acc[0][3] += a0 * b4.w;
      acc[1][0] += a1 * b4.x; acc[1][1] += a1 * b4.y; acc[1][2] += a1 * b4.z; acc[1][3] += a1 * b4.w;
      acc[2][0] += a2 * b4.x; acc[2][1] += a2 * b4.y; acc[2][2] += a2 * b4.z; acc[2][3] += a2 * b4.w;
      acc[3][0] += a3 * b4.x; acc[3][1] += a3 * b4.y; acc[3][2] += a3 * b4.z; acc[3][3] += a3 * b4.w;
    }
    __syncthreads();
  }

#pragma unroll
  for (int j = 0; j < 4; ++j) {
    int m = ty * 4 + j;
    int bn = bn0 + m;
#pragma unroll
    for (int cc = 0; cc < 4; ++cc) {
      int o = tx * 4 + cc;
      float v = acc[j][cc];
#pragma unroll
      for (int d = 0; d < DD; ++d)
        v += emb_lds[m][d] * bias[d * O + o];
      if (MODE == 0) {
        v = 1.f / (1.f + __expf(-v));
        out0[(size_t)bn * 64 + o] = v;
      } else {
        float hc = tanhf(v);
        float r = zr_in[(size_t)bn * 64 + 32 + o];
        float st = state[(size_t)bn * HH + o];
        float res = r * st + (1.f - r) * hc;
        out0[(size_t)bn * HH + o] = res;
        if (out1) out1[(size_t)bn * HH + o] = res;
      }
    }
  }
}

// ---------------------------------------------------------------------------
extern "C" void kernel_launch(void* const* d_in, const int* in_sizes, int n_in,
                              void* d_out, int out_size, void* d_ws, size_t ws_size,
                              hipStream_t stream)
{
  const float* xt         = (const float*)d_in[0];
  const float* init_state = (const float*)d_in[1];
  const float* S          = (const float*)d_in[2];
  const float* emb        = (const float*)d_in[3];

  float* out    = (float*)d_out;          // [BN,32] final cur
  float* hidden = out + (size_t)BN * HH;  // [2, BN, 32]

  float* xg = (float*)d_ws;               // [BN,192]
  float* zr = xg + (size_t)BN * II;       // [BN,64]

  const float* cur = xt;
  for (int l = 0; l < 2; ++l) {
    const float* state = init_state + (size_t)l * BN * HH;
    const float* gw = (const float*)d_in[4 + 4 * l];
    const float* gb = (const float*)d_in[5 + 4 * l];
    const float* uw = (const float*)d_in[6 + 4 * l];
    const float* ub = (const float*)d_in[7 + 4 * l];
    float* hid = hidden + (size_t)l * BN * HH;

    dim3 pg(16, 8);
    // gate gconv: inp = [cur, state]
    build_xg<<<BN * 32 / 256, 256, 0, stream>>>(cur, state, nullptr, xg);
    prop_gemm<<<pg, 256, 0, stream>>>(S, xg, 0, 64, 0);
    prop_gemm<<<pg, 256, 0, stream>>>(S, xg, 64, 128, 1);
    contract_kern<64, 0><<<BN / 64, 256, 0, stream>>>(
        xg, emb, gw, gb, nullptr, nullptr, zr, nullptr);
    // update gconv: cand = [cur, z*state]
    build_xg<<<BN * 32 / 256, 256, 0, stream>>>(cur, state, zr, xg);
    prop_gemm<<<pg, 256, 0, stream>>>(S, xg, 0, 64, 0);
    prop_gemm<<<pg, 256, 0, stream>>>(S, xg, 64, 128, 1);
    contract_kern<32, 1><<<BN / 128, 256, 0, stream>>>(
        xg, emb, uw, ub, zr, state, hid, (l == 1) ? out : nullptr);

    cur = hid;
  }
}

// Round 4
// 539.480 us; speedup vs baseline: 2.2351x; 2.2351x over previous
//
#include <hip/hip_runtime.h>
#include <math.h>

#define BB 8
#define NN 1024
#define HH 32
#define II 192   // K * C = 3*64
#define DD 16
#define BN (BB*NN)

// ---------------------------------------------------------------------------
// build x_g columns [0:64): x_g[:,0:32)=cur, x_g[:,32:64)= state (or z*state)
// ---------------------------------------------------------------------------
__global__ __launch_bounds__(256) void build_xg(
    const float* __restrict__ cur,    // [BN,32]
    const float* __restrict__ state,  // [BN,32]
    const float* __restrict__ zr,     // [BN,64] or nullptr; uses z = zr[:, :32]
    float* __restrict__ xg)           // [BN,192]
{
  int idx = blockIdx.x * 256 + threadIdx.x;   // over BN*32
  int bn = idx >> 5, c = idx & 31;
  float av = cur[idx];
  float sv = state[idx];
  if (zr) sv *= zr[(size_t)bn * 64 + c];
  xg[(size_t)bn * II + c] = av;
  xg[(size_t)bn * II + 32 + c] = sv;
}

// ---------------------------------------------------------------------------
// propagation GEMM, M-tile 32 (grid 32x8 = 256 blocks -> all CUs covered):
//   acc[m, c] = sum_k S[m,k] * xg[b,k, co_in + c]   (c in 0..63)
// mode 0: xg[b,m,co_out+c] = acc
// mode 1: xg[b,m,co_out+c] = 2*acc - xg[b,m,c]   (Chebyshev T2)
// ---------------------------------------------------------------------------
__global__ __launch_bounds__(256) void prop_gemm(
    const float* __restrict__ S,
    float* __restrict__ xg,
    int co_in, int co_out, int mode)
{
  __shared__ float sS[32][33];   // [row][k], padded
  __shared__ float sX[32][64];   // [k][col]
  const int b = blockIdx.y;
  const int m0 = blockIdx.x * 32;
  float* xgb = xg + (size_t)b * NN * II;
  const int tid = threadIdx.x;
  const int tx = tid & 15, ty = tid >> 4;   // tx: 16 col-groups, ty: 16 row-groups
  float acc[2][4] = {};

  for (int k0 = 0; k0 < NN; k0 += 32) {
    {  // S tile: 32 rows x 32 k = 256 float4, one per thread
      int r = tid >> 3;
      int k4 = (tid & 7) << 2;
      float4 v = *(const float4*)(S + (size_t)(m0 + r) * NN + k0 + k4);
      sS[r][k4 + 0] = v.x; sS[r][k4 + 1] = v.y;
      sS[r][k4 + 2] = v.z; sS[r][k4 + 3] = v.w;
    }
#pragma unroll
    for (int q = 0; q < 2; ++q) {  // X tile 32x64 = 512 float4
      int f = tid + q * 256;
      int k = f >> 4;
      int c4 = (f & 15) << 2;
      *(float4*)&sX[k][c4] =
          *(const float4*)(xgb + (size_t)(k0 + k) * II + co_in + c4);
    }
    __syncthreads();
#pragma unroll
    for (int kk = 0; kk < 32; ++kk) {
      float a0 = sS[ty * 2 + 0][kk];
      float a1 = sS[ty * 2 + 1][kk];
      float4 b4 = *(const float4*)&sX[kk][tx * 4];
      acc[0][0] += a0 * b4.x; acc[0][1] += a0 * b4.y; acc[0][2] += a0 * b4.z; acc[0][3] += a0 * b4.w;
      acc[1][0] += a1 * b4.x; acc[1][1] += a1 * b4.y; acc[1][2] += a1 * b4.z; acc[1][3] += a1 * b4.w;
    }
    __syncthreads();
  }

#pragma unroll
  for (int j = 0; j < 2; ++j) {
    int row = m0 + ty * 2 + j;
    float* dst = xgb + (size_t)row * II + co_out + tx * 4;
    if (mode == 0) {
      dst[0] = acc[j][0]; dst[1] = acc[j][1]; dst[2] = acc[j][2]; dst[3] = acc[j][3];
    } else {
      const float* x0 = xgb + (size_t)row * II + tx * 4;
      dst[0] = 2.f * acc[j][0] - x0[0];
      dst[1] = 2.f * acc[j][1] - x0[1];
      dst[2] = 2.f * acc[j][2] - x0[2];
      dst[3] = 2.f * acc[j][3] - x0[3];
    }
  }
}

// ---------------------------------------------------------------------------
// split-K meta contraction over d: block (bx, s) handles d in [s*DPB, (s+1)*DPB)
//   partial[s][bn][o] = sum_{d in range, i} emb[bn,d]*xg[bn,i]*W[d,i,o]
//                       + sum_{d in range} emb[bn,d]*bias[d,o]
// Summing partial over s gives the full pre-activation.
// ---------------------------------------------------------------------------
template <int O, int DPB>
__global__ __launch_bounds__(256) void contract_partial(
    const float* __restrict__ xg,     // [BN,192]
    const float* __restrict__ emb,    // [BN,16]
    const float* __restrict__ W,      // [16,192,O]
    const float* __restrict__ bias,   // [16,O]
    float* __restrict__ partial)      // [16/DPB, BN, O]
{
  constexpr int TXN  = O / 4;        // threads along O
  constexpr int ROWT = 256 / TXN;    // threads along M
  constexpr int MT   = ROWT * 4;     // node tile
  __shared__ float A_lds[MT][97];
  __shared__ float B_lds[96][O];
  __shared__ float emb_lds[MT][17];

  const int bn0 = blockIdx.x * MT;
  const int s = blockIdx.y;
  const int d0 = s * DPB;
  const int tid = threadIdx.x;
  const int tx = tid % TXN, ty = tid / TXN;

  for (int f = tid; f < MT * 4; f += 256) {   // emb tile (MT x 16)
    int m = f >> 2, d4 = (f & 3) << 2;
    float4 v = *(const float4*)(emb + (size_t)(bn0 + m) * DD + d4);
    emb_lds[m][d4 + 0] = v.x; emb_lds[m][d4 + 1] = v.y;
    emb_lds[m][d4 + 2] = v.z; emb_lds[m][d4 + 3] = v.w;
  }
  __syncthreads();

  float acc[4][4] = {};
  for (int c = 0; c < DPB * 2; ++c) {  // chunks of K'=96 (half of one d)
    int d = d0 + (c >> 1);
    int i0 = (c & 1) * 96;
    for (int f = tid; f < MT * 24; f += 256) {   // A tile: emb*xg on the fly
      int m = f / 24;
      int t4 = (f % 24) << 2;
      float4 v = *(const float4*)(xg + (size_t)(bn0 + m) * II + i0 + t4);
      float e = emb_lds[m][d];
      A_lds[m][t4 + 0] = e * v.x; A_lds[m][t4 + 1] = e * v.y;
      A_lds[m][t4 + 2] = e * v.z; A_lds[m][t4 + 3] = e * v.w;
    }
    for (int f = tid; f < 24 * O; f += 256) {    // B tile: W[d, i0..i0+95, :]
      int t = f / TXN;
      int o4 = (f % TXN) << 2;
      *(float4*)&B_lds[t][o4] =
          *(const float4*)(W + ((size_t)d * II + i0 + t) * O + o4);
    }
    __syncthreads();
#pragma unroll 8
    for (int kk = 0; kk < 96; ++kk) {
      float a0 = A_lds[ty * 4 + 0][kk];
      float a1 = A_lds[ty * 4 + 1][kk];
      float a2 = A_lds[ty * 4 + 2][kk];
      float a3 = A_lds[ty * 4 + 3][kk];
      float4 b4 = *(const float4*)&B_lds[kk][tx * 4];
      acc[0][0] += a0 * b4.x; acc[0][1] += a0 * b4.y; acc[0][2] += a0 * b4.z; acc[0][3] += a0 * b4.w;
      acc[1][0] += a1 * b4.x; acc[1][1] += a1 * b4.y; acc[1][2] += a1 * b4.z; acc[1][3] += a1 * b4.w;
      acc[2][0] += a2 * b4.x; acc[2][1] += a2 * b4.y; acc[2][2] += a2 * b4.z; acc[2][3] += a2 * b4.w;
      acc[3][0] += a3 * b4.x; acc[3][1] += a3 * b4.y; acc[3][2] += a3 * b4.z; acc[3][3] += a3 * b4.w;
    }
    __syncthreads();
  }

#pragma unroll
  for (int j = 0; j < 4; ++j) {
    int m = ty * 4 + j;
    int bn = bn0 + m;
#pragma unroll
    for (int cc = 0; cc < 4; ++cc) {
      int o = tx * 4 + cc;
      float v = acc[j][cc];
#pragma unroll
      for (int dd = 0; dd < DPB; ++dd)
        v += emb_lds[m][d0 + dd] * bias[(d0 + dd) * O + o];
      partial[((size_t)s * BN + bn) * O + o] = v;
    }
  }
}

// ---------------------------------------------------------------------------
template <int NS>
__global__ __launch_bounds__(256) void gate_combine(
    const float* __restrict__ partial,  // [NS, BN, 64]
    float* __restrict__ zr)             // [BN, 64]
{
  int idx = blockIdx.x * 256 + threadIdx.x;   // over BN*64
  float v = 0.f;
#pragma unroll
  for (int s = 0; s < NS; ++s) v += partial[(size_t)s * BN * 64 + idx];
  zr[idx] = 1.f / (1.f + __expf(-v));
}

template <int NS>
__global__ __launch_bounds__(256) void upd_combine(
    const float* __restrict__ partial,  // [NS, BN, 32]
    const float* __restrict__ zr,       // [BN, 64]
    const float* __restrict__ state,    // [BN, 32]
    float* __restrict__ hid,
    float* __restrict__ out)            // may be null
{
  int idx = blockIdx.x * 256 + threadIdx.x;   // over BN*32
  int bn = idx >> 5, o = idx & 31;
  float v = 0.f;
#pragma unroll
  for (int s = 0; s < NS; ++s) v += partial[(size_t)s * BN * 32 + idx];
  float hc = tanhf(v);
  float r = zr[(size_t)bn * 64 + 32 + o];
  float st = state[idx];
  float res = r * st + (1.f - r) * hc;
  hid[idx] = res;
  if (out) out[idx] = res;
}

// ---------------------------------------------------------------------------
extern "C" void kernel_launch(void* const* d_in, const int* in_sizes, int n_in,
                              void* d_out, int out_size, void* d_ws, size_t ws_size,
                              hipStream_t stream)
{
  const float* xt         = (const float*)d_in[0];
  const float* init_state = (const float*)d_in[1];
  const float* S          = (const float*)d_in[2];
  const float* emb        = (const float*)d_in[3];

  float* out    = (float*)d_out;          // [BN,32] final cur
  float* hidden = out + (size_t)BN * HH;  // [2, BN, 32]

  float* xg      = (float*)d_ws;              // [BN,192]       6 MB
  float* zr      = xg + (size_t)BN * II;      // [BN,64]        2 MB
  float* partial = zr + (size_t)BN * 64;      // [<=2M floats]  8 MB

  const float* cur = xt;
  for (int l = 0; l < 2; ++l) {
    const float* state = init_state + (size_t)l * BN * HH;
    const float* gw = (const float*)d_in[4 + 4 * l];
    const float* gb = (const float*)d_in[5 + 4 * l];
    const float* uw = (const float*)d_in[6 + 4 * l];
    const float* ub = (const float*)d_in[7 + 4 * l];
    float* hid = hidden + (size_t)l * BN * HH;

    dim3 pg(NN / 32, BB);   // 32 x 8 = 256 blocks
    // gate gconv: inp = [cur, state]
    build_xg<<<BN * 32 / 256, 256, 0, stream>>>(cur, state, nullptr, xg);
    prop_gemm<<<pg, 256, 0, stream>>>(S, xg, 0, 64, 0);
    prop_gemm<<<pg, 256, 0, stream>>>(S, xg, 64, 128, 1);
    contract_partial<64, 4><<<dim3(BN / 64, 4), 256, 0, stream>>>(
        xg, emb, gw, gb, partial);                     // 512 blocks
    gate_combine<4><<<BN * 64 / 256, 256, 0, stream>>>(partial, zr);
    // update gconv: cand = [cur, z*state]
    build_xg<<<BN * 32 / 256, 256, 0, stream>>>(cur, state, zr, xg);
    prop_gemm<<<pg, 256, 0, stream>>>(S, xg, 0, 64, 0);
    prop_gemm<<<pg, 256, 0, stream>>>(S, xg, 64, 128, 1);
    contract_partial<32, 2><<<dim3(BN / 128, 8), 256, 0, stream>>>(
        xg, emb, uw, ub, partial);                     // 512 blocks
    upd_combine<8><<<BN * 32 / 256, 256, 0, stream>>>(
        partial, zr, state, hid, (l == 1) ? out : nullptr);

    cur = hid;
  }
}

// Round 5
// 448.746 us; speedup vs baseline: 2.6870x; 1.2022x over previous
//
#include <hip/hip_runtime.h>
#include <math.h>

#define BB 8
#define NN 1024
#define HH 32
#define II 192   // K * C = 3*64
#define DD 16
#define BN (BB*NN)

typedef __attribute__((ext_vector_type(8))) short short8v;   // 8 bf16 (4 VGPRs)
typedef __attribute__((ext_vector_type(4))) float float4v;   // MFMA C/D

union Frag8 { short8v v; uint2 u[2]; };

// fp32 -> bf16 round-to-nearest-even (finite inputs)
static __device__ inline ushort bf(float x) {
  union { float f; unsigned u; } c; c.f = x;
  unsigned r = c.u + 0x7FFFu + ((c.u >> 16) & 1u);
  return (ushort)(r >> 16);
}

// ---------------------------------------------------------------------------
// build x_g columns [0:64): x_g[:,0:32)=cur, x_g[:,32:64)= state (or z*state)
// ---------------------------------------------------------------------------
__global__ __launch_bounds__(256) void build_xg(
    const float* __restrict__ cur,    // [BN,32]
    const float* __restrict__ state,  // [BN,32]
    const float* __restrict__ zr,     // [BN,64] or nullptr; uses z = zr[:, :32]
    float* __restrict__ xg)           // [BN,192]
{
  int idx = blockIdx.x * 256 + threadIdx.x;   // over BN*32
  int bn = idx >> 5, c = idx & 31;
  float av = cur[idx];
  float sv = state[idx];
  if (zr) sv *= zr[(size_t)bn * 64 + c];
  xg[(size_t)bn * II + c] = av;
  xg[(size_t)bn * II + 32 + c] = sv;
}

// ---------------------------------------------------------------------------
// propagation GEMM, M-tile 32 (grid 32x8 = 256 blocks):
//   acc[m, c] = sum_k S[m,k] * xg[b,k, co_in + c]   (c in 0..63)
// mode 0: xg[b,m,co_out+c] = acc
// mode 1: xg[b,m,co_out+c] = 2*acc - xg[b,m,c]   (Chebyshev T2)
// ---------------------------------------------------------------------------
__global__ __launch_bounds__(256) void prop_gemm(
    const float* __restrict__ S,
    float* __restrict__ xg,
    int co_in, int co_out, int mode)
{
  __shared__ float sS[32][33];   // [row][k], padded
  __shared__ float sX[32][64];   // [k][col]
  const int b = blockIdx.y;
  const int m0 = blockIdx.x * 32;
  float* xgb = xg + (size_t)b * NN * II;
  const int tid = threadIdx.x;
  const int tx = tid & 15, ty = tid >> 4;
  float acc[2][4] = {};

  for (int k0 = 0; k0 < NN; k0 += 32) {
    {  // S tile: 32 rows x 32 k = 256 float4, one per thread
      int r = tid >> 3;
      int k4 = (tid & 7) << 2;
      float4 v = *(const float4*)(S + (size_t)(m0 + r) * NN + k0 + k4);
      sS[r][k4 + 0] = v.x; sS[r][k4 + 1] = v.y;
      sS[r][k4 + 2] = v.z; sS[r][k4 + 3] = v.w;
    }
#pragma unroll
    for (int q = 0; q < 2; ++q) {  // X tile 32x64 = 512 float4
      int f = tid + q * 256;
      int k = f >> 4;
      int c4 = (f & 15) << 2;
      *(float4*)&sX[k][c4] =
          *(const float4*)(xgb + (size_t)(k0 + k) * II + co_in + c4);
    }
    __syncthreads();
#pragma unroll
    for (int kk = 0; kk < 32; ++kk) {
      float a0 = sS[ty * 2 + 0][kk];
      float a1 = sS[ty * 2 + 1][kk];
      float4 b4 = *(const float4*)&sX[kk][tx * 4];
      acc[0][0] += a0 * b4.x; acc[0][1] += a0 * b4.y; acc[0][2] += a0 * b4.z; acc[0][3] += a0 * b4.w;
      acc[1][0] += a1 * b4.x; acc[1][1] += a1 * b4.y; acc[1][2] += a1 * b4.z; acc[1][3] += a1 * b4.w;
    }
    __syncthreads();
  }

#pragma unroll
  for (int j = 0; j < 2; ++j) {
    int row = m0 + ty * 2 + j;
    float* dst = xgb + (size_t)row * II + co_out + tx * 4;
    if (mode == 0) {
      dst[0] = acc[j][0]; dst[1] = acc[j][1]; dst[2] = acc[j][2]; dst[3] = acc[j][3];
    } else {
      const float* x0 = xgb + (size_t)row * II + tx * 4;
      dst[0] = 2.f * acc[j][0] - x0[0];
      dst[1] = 2.f * acc[j][1] - x0[1];
      dst[2] = 2.f * acc[j][2] - x0[2];
      dst[3] = 2.f * acc[j][3] - x0[3];
    }
  }
}

// ---------------------------------------------------------------------------
// weight prep: W[d][i][o] f32  ->  Wt[d][o][i] bf16   (one block per d)
// ---------------------------------------------------------------------------
template <int O>
__global__ __launch_bounds__(256) void prep_w(
    const float* __restrict__ W,
    ushort* __restrict__ Wt)
{
  __shared__ float lds[II][O + 1];
  const int d = blockIdx.x;
  const float* Wd = W + (size_t)d * II * O;
  ushort* Wtd = Wt + (size_t)d * O * II;
  const int tid = threadIdx.x;
  for (int f = tid; f < II * O / 4; f += 256) {   // coalesced f32 loads
    int i = f / (O / 4);
    int o4 = (f % (O / 4)) * 4;
    float4 v = *(const float4*)(Wd + (size_t)i * O + o4);
    lds[i][o4 + 0] = v.x; lds[i][o4 + 1] = v.y;
    lds[i][o4 + 2] = v.z; lds[i][o4 + 3] = v.w;
  }
  __syncthreads();
  for (int h = tid; h < II * O / 2; h += 256) {   // coalesced bf16-pair stores
    int o = h / (II / 2);
    int i2 = (h % (II / 2)) * 2;
    unsigned p = (unsigned)bf(lds[i2][o]) | ((unsigned)bf(lds[i2 + 1][o]) << 16);
    *(unsigned*)(Wtd + (size_t)o * II + i2) = p;
  }
}

// ---------------------------------------------------------------------------
// MFMA meta contraction, fused activation/GRU epilogue.
//   out[m,o] = act( sum_d emb[m,d] * ( (xg[m,:] @ W[d])[o] + bias[d,o] ) )
// Block: 128 threads (2 waves), M-tile 32 (wave w -> rows w*16..w*16+15).
// A = xg tile bf16 in LDS [32][200]; B = Wt[d] bf16 in LDS [O][200].
// mfma_f32_16x16x32_bf16 operand mapping (m89/m162):
//   A: lane l elem e -> A[l&15][(e>>2)*16 + (l>>4)*4 + (e&3)]
//   B: lane l elem e -> B-row (l&15)+16*frag, same k
//   C: col=lane&15 (+16*frag), row=(lane>>4)*4+reg
// MODE 0 (gate, O=64): out0[m*64+o] = sigmoid(v)
// MODE 1 (upd,  O=32): hc=tanh(v); r=zr[m*64+32+o]; res=r*st+(1-r)*hc
// ---------------------------------------------------------------------------
template <int O, int MODE>
__global__ __launch_bounds__(128) void contract_mfma(
    const float* __restrict__ xg,     // [BN,192]
    const float* __restrict__ emb,    // [BN,16]
    const ushort* __restrict__ Wt,    // [16][O][192] bf16
    const float* __restrict__ bias,   // [16][O]
    const float* __restrict__ zr_in,  // [BN,64]  (MODE 1)
    const float* __restrict__ state,  // [BN,32]  (MODE 1)
    float* __restrict__ out0,
    float* __restrict__ out1)         // may be null
{
  constexpr int NF = O / 16;                  // col fragments per wave
  __shared__ ushort A_lds[32][200];           // +8 pad: 2-way banks max
  __shared__ ushort B_lds[O][200];
  __shared__ float emb_lds[32][17];
  __shared__ float bias_lds[16][O];

  const int bn0 = blockIdx.x * 32;
  const int tid = threadIdx.x;
  const int w = tid >> 6;                     // wave 0/1
  const int l = tid & 63;
  const int l15 = l & 15, l4 = l >> 4;

  // ---- stage A: xg[bn0..bn0+31][0..191] -> bf16
#pragma unroll
  for (int q = 0; q < 12; ++q) {              // 1536 float4 chunks
    int f = tid + q * 128;
    int row = f / 48;
    int k4 = (f % 48) * 4;
    float4 v = *(const float4*)(xg + (size_t)(bn0 + row) * II + k4);
    ushort4 b4; b4.x = bf(v.x); b4.y = bf(v.y); b4.z = bf(v.z); b4.w = bf(v.w);
    *(ushort4*)&A_lds[row][k4] = b4;
  }
  // ---- stage emb [32][16]
  {
    int row = tid / 4, d4 = (tid % 4) * 4;
    float4 v = *(const float4*)(emb + (size_t)(bn0 + row) * DD + d4);
    emb_lds[row][d4 + 0] = v.x; emb_lds[row][d4 + 1] = v.y;
    emb_lds[row][d4 + 2] = v.z; emb_lds[row][d4 + 3] = v.w;
  }
  // ---- stage bias [16][O]
  for (int f = tid; f < DD * O / 4; f += 128) {
    int d = f / (O / 4), o4 = (f % (O / 4)) * 4;
    *(float4*)&bias_lds[d][o4] = *(const float4*)(bias + (size_t)d * O + o4);
  }

  float4v outacc[NF];
#pragma unroll
  for (int f = 0; f < NF; ++f) outacc[f] = (float4v){0.f, 0.f, 0.f, 0.f};

  const int arow = w * 16 + l15;
  const int erow = w * 16 + l4 * 4;

  for (int d = 0; d < DD; ++d) {
    __syncthreads();   // d=0: staging done; d>0: all waves done reading B_lds
    // ---- stage B = Wt[d] : [O][192] bf16, 16B chunks, coalesced
    const ushort* Wtd = Wt + (size_t)d * O * II;
#pragma unroll
    for (int q = 0; q < (O * II / 8) / 128; ++q) {
      int f = tid + q * 128;
      int o = f / 24;
      int k8 = (f % 24) * 8;
      uint4 v = *(const uint4*)(Wtd + (size_t)o * II + k8);
      *(uint4*)&B_lds[o][k8] = v;
    }
    __syncthreads();

    float4v acc[NF];
#pragma unroll
    for (int f = 0; f < NF; ++f) acc[f] = (float4v){0.f, 0.f, 0.f, 0.f};
#pragma unroll
    for (int ks = 0; ks < 6; ++ks) {
      int kb = ks * 32 + l4 * 4;
      Frag8 af;
      af.u[0] = *(const uint2*)&A_lds[arow][kb];
      af.u[1] = *(const uint2*)&A_lds[arow][kb + 16];
#pragma unroll
      for (int f = 0; f < NF; ++f) {
        Frag8 bfr;
        bfr.u[0] = *(const uint2*)&B_lds[l15 + 16 * f][kb];
        bfr.u[1] = *(const uint2*)&B_lds[l15 + 16 * f][kb + 16];
        acc[f] = __builtin_amdgcn_mfma_f32_16x16x32_bf16(af.v, bfr.v, acc[f], 0, 0, 0);
      }
    }
    // ---- fold: out += emb[row,d] * (acc + bias[d,col])
    float e0 = emb_lds[erow + 0][d];
    float e1 = emb_lds[erow + 1][d];
    float e2 = emb_lds[erow + 2][d];
    float e3 = emb_lds[erow + 3][d];
#pragma unroll
    for (int f = 0; f < NF; ++f) {
      float bb = bias_lds[d][l15 + 16 * f];
      outacc[f][0] += e0 * (acc[f][0] + bb);
      outacc[f][1] += e1 * (acc[f][1] + bb);
      outacc[f][2] += e2 * (acc[f][2] + bb);
      outacc[f][3] += e3 * (acc[f][3] + bb);
    }
  }

  // ---- fused epilogue
#pragma unroll
  for (int f = 0; f < NF; ++f) {
#pragma unroll
    for (int r = 0; r < 4; ++r) {
      int m = bn0 + erow + r;
      int col = l15 + 16 * f;
      float v = outacc[f][r];
      if (MODE == 0) {
        out0[(size_t)m * 64 + col] = 1.f / (1.f + __expf(-v));
      } else {
        float hc = tanhf(v);
        float rg = zr_in[(size_t)m * 64 + 32 + col];
        float st = state[(size_t)m * HH + col];
        float res = rg * st + (1.f - rg) * hc;
        out0[(size_t)m * HH + col] = res;
        if (out1) out1[(size_t)m * HH + col] = res;
      }
    }
  }
}

// ---------------------------------------------------------------------------
extern "C" void kernel_launch(void* const* d_in, const int* in_sizes, int n_in,
                              void* d_out, int out_size, void* d_ws, size_t ws_size,
                              hipStream_t stream)
{
  const float* xt         = (const float*)d_in[0];
  const float* init_state = (const float*)d_in[1];
  const float* S          = (const float*)d_in[2];
  const float* emb        = (const float*)d_in[3];

  float* out    = (float*)d_out;          // [BN,32] final cur
  float* hidden = out + (size_t)BN * HH;  // [2, BN, 32]

  float* xg = (float*)d_ws;                      // [BN,192] f32   6.0 MB
  float* zr = xg + (size_t)BN * II;              // [BN,64]  f32   2.0 MB
  ushort* wtg0 = (ushort*)(zr + (size_t)BN * 64);  // bf16 weights  1.2 MB
  ushort* wtu0 = wtg0 + (size_t)DD * II * 64;
  ushort* wtg1 = wtu0 + (size_t)DD * II * 32;
  ushort* wtu1 = wtg1 + (size_t)DD * II * 64;

  // weight prep (static inputs; recomputed every call for determinism)
  prep_w<64><<<DD, 256, 0, stream>>>((const float*)d_in[4], wtg0);
  prep_w<32><<<DD, 256, 0, stream>>>((const float*)d_in[6], wtu0);
  prep_w<64><<<DD, 256, 0, stream>>>((const float*)d_in[8], wtg1);
  prep_w<32><<<DD, 256, 0, stream>>>((const float*)d_in[10], wtu1);

  const float* cur = xt;
  for (int l = 0; l < 2; ++l) {
    const float* state = init_state + (size_t)l * BN * HH;
    const float* gb = (const float*)d_in[5 + 4 * l];
    const float* ub = (const float*)d_in[7 + 4 * l];
    const ushort* wtg = (l == 0) ? wtg0 : wtg1;
    const ushort* wtu = (l == 0) ? wtu0 : wtu1;
    float* hid = hidden + (size_t)l * BN * HH;

    dim3 pg(NN / 32, BB);   // 32 x 8 = 256 blocks
    // gate gconv: inp = [cur, state]
    build_xg<<<BN * 32 / 256, 256, 0, stream>>>(cur, state, nullptr, xg);
    prop_gemm<<<pg, 256, 0, stream>>>(S, xg, 0, 64, 0);
    prop_gemm<<<pg, 256, 0, stream>>>(S, xg, 64, 128, 1);
    contract_mfma<64, 0><<<BN / 32, 128, 0, stream>>>(
        xg, emb, wtg, gb, nullptr, nullptr, zr, nullptr);
    // update gconv: cand = [cur, z*state]
    build_xg<<<BN * 32 / 256, 256, 0, stream>>>(cur, state, zr, xg);
    prop_gemm<<<pg, 256, 0, stream>>>(S, xg, 0, 64, 0);
    prop_gemm<<<pg, 256, 0, stream>>>(S, xg, 64, 128, 1);
    contract_mfma<32, 1><<<BN / 32, 128, 0, stream>>>(
        xg, emb, wtu, ub, zr, state, hid, (l == 1) ? out : nullptr);

    cur = hid;
  }
}